// Round 7
// baseline (124.149 us; speedup 1.0000x reference)
//
#include <hip/hip_runtime.h>
#include <stdint.h>

#define EPSF 1e-8f

using i32x4  = __attribute__((ext_vector_type(4))) int;
using i32x16 = __attribute__((ext_vector_type(16))) int;

__device__ __forceinline__ float wave_sum(float v) {
#pragma unroll
  for (int off = 32; off > 0; off >>= 1) v += __shfl_down(v, off, 64);
  return v;
}
__device__ __forceinline__ float wave_max(float v) {
#pragma unroll
  for (int off = 32; off > 0; off >>= 1) v = fmaxf(v, __shfl_down(v, off, 64));
  return v;
}

// ---------------- weight ternary quant (i8) + per-row scale ----------------
// mask |w|>0.5*mean|w| invariant to row RMSNorm; ternary {-1,0,1} exact in i8.
// scale[o] = mean|w| * rsqrt(mean(w^2)+EPS) * row_scale[o]
__global__ __launch_bounds__(256) void wquant_kernel(
    const float* __restrict__ w, const float* __restrict__ row_scale,
    signed char* __restrict__ wq, float* __restrict__ scale, int K) {
  const int row = blockIdx.x;
  const int t = threadIdx.x;
  const float* wr = w + (size_t)row * K;
  float4 v0 = reinterpret_cast<const float4*>(wr)[2 * t];
  float4 v1 = reinterpret_cast<const float4*>(wr)[2 * t + 1];
  float f[8] = {v0.x, v0.y, v0.z, v0.w, v1.x, v1.y, v1.z, v1.w};
  float sa = 0.f, sq = 0.f;
#pragma unroll
  for (int i = 0; i < 8; ++i) { sa += fabsf(f[i]); sq += f[i] * f[i]; }
  sa = wave_sum(sa);
  sq = wave_sum(sq);
  __shared__ float smA[4], smQ[4];
  const int wid = t >> 6;
  if ((t & 63) == 0) { smA[wid] = sa; smQ[wid] = sq; }
  __syncthreads();
  const float sumabs = smA[0] + smA[1] + smA[2] + smA[3];
  const float sumsq  = smQ[0] + smQ[1] + smQ[2] + smQ[3];
  const float absmean = sumabs / (float)K;
  const float thr = 0.5f * absmean;
  union { signed char c[8]; uint2 u; } pk;
#pragma unroll
  for (int i = 0; i < 8; ++i)
    pk.c[i] = (fabsf(f[i]) > thr) ? (f[i] > 0.f ? (signed char)1 : (signed char)-1)
                                  : (signed char)0;
  reinterpret_cast<uint2*>(wq + (size_t)row * K)[t] = pk.u;
  if (t == 0)
    scale[row] = absmean * rsqrtf(sumsq / (float)K + EPSF) * row_scale[row];
}

// ---------------- input RMSNorm * g -> i8 (per-row symmetric) ----------------
__global__ __launch_bounds__(256) void xnorm_kernel(
    const float* __restrict__ x, const float* __restrict__ g,
    signed char* __restrict__ xq, float* __restrict__ sx, int K) {
  const int row = blockIdx.x;
  const int t = threadIdx.x;
  const float* xr = x + (size_t)row * K;
  float4 v0 = reinterpret_cast<const float4*>(xr)[2 * t];
  float4 v1 = reinterpret_cast<const float4*>(xr)[2 * t + 1];
  float f[8] = {v0.x, v0.y, v0.z, v0.w, v1.x, v1.y, v1.z, v1.w};
  float sq = 0.f;
#pragma unroll
  for (int i = 0; i < 8; ++i) sq += f[i] * f[i];
  sq = wave_sum(sq);
  __shared__ float smQ[4], smM[4];
  const int wid = t >> 6;
  if ((t & 63) == 0) smQ[wid] = sq;
  __syncthreads();
  const float sumsq = smQ[0] + smQ[1] + smQ[2] + smQ[3];
  const float rs = rsqrtf(sumsq / (float)K + EPSF);
  float4 g0 = reinterpret_cast<const float4*>(g)[2 * t];
  float4 g1 = reinterpret_cast<const float4*>(g)[2 * t + 1];
  float gg[8] = {g0.x, g0.y, g0.z, g0.w, g1.x, g1.y, g1.z, g1.w};
  float vv[8]; float am = 0.f;
#pragma unroll
  for (int i = 0; i < 8; ++i) {
    vv[i] = f[i] * rs * gg[i];
    am = fmaxf(am, fabsf(vv[i]));
  }
  am = wave_max(am);
  if ((t & 63) == 0) smM[wid] = am;
  __syncthreads();
  const float amax = fmaxf(fmaxf(smM[0], smM[1]), fmaxf(smM[2], smM[3]));
  const float inv = amax > 0.f ? 127.f / amax : 0.f;
  union { signed char c[8]; uint2 u; } pk;
#pragma unroll
  for (int i = 0; i < 8; ++i)
    pk.c[i] = (signed char)__float2int_rn(vv[i] * inv);
  reinterpret_cast<uint2*>(xq + (size_t)row * K)[t] = pk.u;
  if (t == 0) sx[row] = amax > 0.f ? amax / 127.f : 0.f;
}

// ---------------- i8 NT GEMM, 256x256 tile, 8-phase pipeline ----------------
// C[m,n] = sx[m]*scale[n]*sum_k qA[m,k]*t[n,k] + bias[n]; i32 dot is exact.
// 512 threads = 8 waves (2M x 4N); per-wave 128x64; BK=128 i8.
// ROUND-7 change: mfma_i32_32x32x32_i8 (was 16x16x64). Per quadrant phase:
// 8 MFMA (2 m-tiles x 4 k-steps) instead of 16; +11.7% ceiling (4404 vs
// 3944 TOPS), half the issue slots. ds_read pattern/count unchanged
// (12/4/8/0 b128 per phase), staging/vmcnt/barriers frozen from R6.
//  * Fragment: A row=lane&31 of its 32-row tile, 16 i8 at k = (lane>>5)*16
//    + s*32; B mirrored (col=lane&31). A/B same (lane,byte)->k map =>
//    internal k-permutation cancels in the dot product.
//  * C/D layout (m74/m101 verified): col=lane&31,
//    row = (reg&3) + 8*(reg>>2) + 4*(lane>>5), reg in [0,16).
//  * XOR swizzle: stored slot for granule g at lds row r is g ^ (r&7);
//    read granule g = s*2 + (lane>>5), row&7 = lane&7 for all tiles
//    (32|64-row strides = 0 mod 8), so read byte = slotB0 ^ (s<<5) with
//    slotB0 = ((lane>>5) ^ (lane&7)) << 4. Staging source granule
//    (tid&7) ^ (sr&7) unchanged (both-sides-or-neither).
//  * bF holds BOTH np halves (R4 lesson: P3/P7 consume np=0 loaded at P1/P5).
// Steady-state vmcnt FIFO (1 stage = 2 gld_lds): enter P1 with 8
// {S5..S8}(j-1); P1 +S1=10, VM(6) drains S5,S6 (read P2/P3); P4 +S2..S4=12,
// VM(8) drains S7,S8 (read P5); P5 +S5=10, VM(6) drains S1,S2 (read P6/P7);
// P8 +S6..S8=12, VM(8) drains S3,S4 (read next P1).
// Peel: P1 VM(6) [10->6], P4 VM(4) [6->4], P5 VM(0).

#define BAR() do { __builtin_amdgcn_sched_barrier(0); \
                   asm volatile("" ::: "memory"); \
                   __builtin_amdgcn_s_barrier(); \
                   asm volatile("" ::: "memory"); \
                   __builtin_amdgcn_sched_barrier(0); } while (0)
#define VM(n) asm volatile("s_waitcnt vmcnt(" #n ")" ::: "memory")

__global__ __launch_bounds__(512, 2) void gemm_kernel(
    const signed char* __restrict__ A,   // [M][K] i8 (xq)
    const signed char* __restrict__ B,   // [N][K] i8 ternary (wq)
    const float* __restrict__ scale, const float* __restrict__ bias,
    const float* __restrict__ sx,
    float* __restrict__ C, int M, int N, int K) {
  __shared__ signed char lds[2][2][2][16384];

  const int tid  = threadIdx.x;
  const int lane = tid & 63;
  const int wid  = tid >> 6;
  const int wm   = wid >> 2;   // 0..1
  const int wn   = wid & 3;    // 0..3
  const int l31  = lane & 31;
  const int b5   = lane >> 5;

  // chunked XCD swizzle (round-2 mapping: all 8 bn co-resident per XCD)
  const int nwg = gridDim.x;
  const int cpx = nwg >> 3;
  const int swz = (blockIdx.x & 7) * cpx + (blockIdx.x >> 3);
  const int NBN = N >> 8;
  const int bn = swz % NBN;
  const int bm = swz / NBN;
  const int mBase = bm * 256, nBase = bn * 256;

  const size_t Kb = (size_t)K;  // bytes per row (i8)

  // ---- staging constants: thread t -> lds row sr=t>>3, granule slot t&7;
  // XOR-inverse source granule (same for +64-row second load: 64&7==0).
  const int sr = tid >> 3;                           // 0..63
  const int gsrc = (tid & 7) ^ (sr & 7);             // global granule
  const char* Abyte = (const char*)A + (size_t)(mBase + sr) * Kb + gsrc * 16;
  const char* Bbyte = (const char*)B +
      (size_t)(nBase + ((sr >> 5) * 64) + (sr & 31)) * Kb + gsrc * 16;

#define STAGE_A(bufi, h, t) do { \
    __builtin_amdgcn_global_load_lds( \
      (const __attribute__((address_space(1))) void*)(Abyte + (size_t)((h) * 64) * Kb + (size_t)(t) * 128), \
      (__attribute__((address_space(3))) void*)(&lds[bufi][0][h][tid * 16]), 16, 0, 0); \
    __builtin_amdgcn_global_load_lds( \
      (const __attribute__((address_space(1))) void*)(Abyte + (size_t)(128 + (h) * 64) * Kb + (size_t)(t) * 128), \
      (__attribute__((address_space(3))) void*)(&lds[bufi][0][h][8192 + tid * 16]), 16, 0, 0); \
  } while (0)

#define STAGE_B(bufi, h, t) do { \
    __builtin_amdgcn_global_load_lds( \
      (const __attribute__((address_space(1))) void*)(Bbyte + (size_t)((h) * 32) * Kb + (size_t)(t) * 128), \
      (__attribute__((address_space(3))) void*)(&lds[bufi][1][h][tid * 16]), 16, 0, 0); \
    __builtin_amdgcn_global_load_lds( \
      (const __attribute__((address_space(1))) void*)(Bbyte + (size_t)(128 + (h) * 32) * Kb + (size_t)(t) * 128), \
      (__attribute__((address_space(3))) void*)(&lds[bufi][1][h][8192 + tid * 16]), 16, 0, 0); \
  } while (0)

  // ---- reader constants (XOR perm on ds_read; row&7 == lane&7 always) ----
  const int slotB0 = ((b5 ^ (lane & 7)) << 4);  // byte offset, s=0
  const int aRowB = (wm * 64 + l31) * 128;      // A lds row byte base (mt2=0)
  const int bRowB = (wn * 32 + l31) * 128;      // B lds row byte base

  i32x4 aF[2][4], bF[2][4];
  i32x16 acc[4][2];
#pragma unroll
  for (int m = 0; m < 4; ++m)
#pragma unroll
    for (int n = 0; n < 2; ++n)
#pragma unroll
      for (int r = 0; r < 16; ++r) acc[m][n][r] = 0;

#define LDA(bufi, mg) do { \
    _Pragma("unroll") for (int mt2 = 0; mt2 < 2; ++mt2) \
    _Pragma("unroll") for (int s = 0; s < 4; ++s) \
      aF[mt2][s] = *(const i32x4*)&lds[bufi][0][mg][ \
          aRowB + mt2 * 4096 + (slotB0 ^ (s << 5))]; \
  } while (0)

#define LDB(bufi, np) do { \
    _Pragma("unroll") for (int s = 0; s < 4; ++s) \
      bF[np][s] = *(const i32x4*)&lds[bufi][1][np][ \
          bRowB + (slotB0 ^ (s << 5))]; \
  } while (0)

#define MFMA_Q(mg, np) do { \
    __builtin_amdgcn_s_setprio(1); \
    _Pragma("unroll") for (int s = 0; s < 4; ++s) \
    _Pragma("unroll") for (int mt2 = 0; mt2 < 2; ++mt2) \
      acc[(mg) * 2 + mt2][np] = __builtin_amdgcn_mfma_i32_32x32x32_i8( \
          aF[mt2][s], bF[np][s], acc[(mg) * 2 + mt2][np], 0, 0, 0); \
    __builtin_amdgcn_s_setprio(0); } while (0)

  const int crow32 = mBase + wm * 128 + 4 * b5;  // + mg*64 + mt2*32 + rowmap
  const int ccol32 = nBase + wn * 64 + l31;      // + np*32

#define STORE_Q(mg, np) do { \
    const int gc = ccol32 + (np) * 32; \
    const float sc = scale[gc]; \
    const float bi = bias[gc]; \
    _Pragma("unroll") for (int mt2 = 0; mt2 < 2; ++mt2) { \
      const int rb = crow32 + (mg) * 64 + mt2 * 32; \
      float sxv[16]; \
      _Pragma("unroll") for (int reg = 0; reg < 16; ++reg) \
        sxv[reg] = sx[rb + (reg & 3) + 8 * (reg >> 2)]; \
      _Pragma("unroll") for (int reg = 0; reg < 16; ++reg) { \
        const int r = rb + (reg & 3) + 8 * (reg >> 2); \
        C[(size_t)r * (size_t)N + (size_t)gc] = \
            (float)acc[(mg) * 2 + mt2][np][reg] * (sxv[reg] * sc) + bi; \
      } } } while (0)

  // ---- prologue: tile0 complete, tile1 h0 halves ----
  STAGE_A(0, 0, 0); STAGE_B(0, 0, 0);
  STAGE_A(0, 1, 0); STAGE_B(0, 1, 0);
  STAGE_A(1, 0, 1); STAGE_B(1, 0, 1);
  VM(8);
  BAR();

  const int NT = K >> 7;  // 128-wide K-tiles; 2048/128 = 16; 7 iters + peel
  for (int i = 0; i < (NT >> 1) - 1; ++i) {
    const int t1  = 2 * i + 1;
    const int tn0 = 2 * i + 2;
    const int tn1 = 2 * i + 3;
    // P1
    LDA(0, 0); LDB(0, 0); STAGE_A(1, 1, t1); VM(6);
    BAR(); MFMA_Q(0, 0);
    // P2
    LDB(0, 1); STAGE_B(1, 1, t1);
    BAR(); MFMA_Q(0, 1);
    // P3
    LDA(0, 1); STAGE_A(0, 0, tn0);
    BAR(); MFMA_Q(1, 0);
    // P4
    STAGE_B(0, 0, tn0); VM(8);
    BAR(); MFMA_Q(1, 1);
    // P5
    LDA(1, 0); LDB(1, 0); STAGE_A(0, 1, tn0); VM(6);
    BAR(); MFMA_Q(0, 0);
    // P6
    LDB(1, 1); STAGE_B(0, 1, tn0);
    BAR(); MFMA_Q(0, 1);
    // P7
    LDA(1, 1); STAGE_A(1, 0, tn1);
    BAR(); MFMA_Q(1, 0);
    // P8
    STAGE_B(1, 0, tn1); VM(8);
    BAR(); MFMA_Q(1, 1);
  }

  // ---- peeled last iteration (tiles NT-2 in buf0, NT-1 in buf1) ----
  {
    const int tl = NT - 1;
    // P1: stage buf1 h1 (still needed by P6/P7)
    LDA(0, 0); LDB(0, 0); STAGE_A(1, 1, tl); VM(6);
    BAR(); MFMA_Q(0, 0);
    // P2
    LDB(0, 1); STAGE_B(1, 1, tl);
    BAR(); MFMA_Q(0, 1);
    // P3
    LDA(0, 1);
    BAR(); MFMA_Q(1, 0);
    // P4: drain buf1 h0 pair -> 2 stages left
    VM(4);
    BAR(); MFMA_Q(1, 1);
    // P5: drain remaining; quadrants final from here -> store inline
    LDA(1, 0); LDB(1, 0); VM(0);
    BAR(); MFMA_Q(0, 0); STORE_Q(0, 0);
    // P6
    LDB(1, 1);
    BAR(); MFMA_Q(0, 1); STORE_Q(0, 1);
    // P7
    LDA(1, 1);
    BAR(); MFMA_Q(1, 0); STORE_Q(1, 0);
    // P8
    BAR(); MFMA_Q(1, 1); STORE_Q(1, 1);
  }
#undef STAGE_A
#undef STAGE_B
#undef LDA
#undef LDB
#undef MFMA_Q
#undef STORE_Q
}

extern "C" void kernel_launch(void* const* d_in, const int* in_sizes, int n_in,
                              void* d_out, int out_size, void* d_ws, size_t ws_size,
                              hipStream_t stream) {
  const float* x         = (const float*)d_in[0];  // [B,S,Din]
  const float* weight    = (const float*)d_in[1];  // [Dout,Din]
  const float* row_scale = (const float*)d_in[2];  // [Dout,1]
  const float* bias      = (const float*)d_in[3];  // [Dout]
  const float* g         = (const float*)d_in[4];  // [Din]
  float* out = (float*)d_out;

  const int Din  = in_sizes[4];         // 2048
  const int Dout = in_sizes[3];         // 2048
  const int Mrows = in_sizes[0] / Din;  // 16384

  // ws: wq i8 [Dout*Din] | xq i8 [M*Din] | scale f32 [Dout] | sx f32 [M]
  char* ws = (char*)d_ws;
  signed char* wq = (signed char*)ws;
  signed char* xq = (signed char*)(ws + (size_t)Dout * Din);
  float* scale = (float*)(ws + (size_t)Dout * Din + (size_t)Mrows * Din);
  float* sx = scale + Dout;

  wquant_kernel<<<Dout, 256, 0, stream>>>(weight, row_scale, wq, scale, Din);
  xnorm_kernel<<<Mrows, 256, 0, stream>>>(x, g, xq, sx, Din);
  const int grid = (Mrows / 256) * (Dout / 256);
  gemm_kernel<<<grid, 512, 0, stream>>>(xq, wq, scale, bias, sx, out,
                                        Mrows, Dout, Din);
}

// Round 8
// 116.401 us; speedup vs baseline: 1.0666x; 1.0666x over previous
//
#include <hip/hip_runtime.h>
#include <stdint.h>

#define EPSF 1e-8f

using i32x4 = __attribute__((ext_vector_type(4))) int;

__device__ __forceinline__ float wave_sum(float v) {
#pragma unroll
  for (int off = 32; off > 0; off >>= 1) v += __shfl_down(v, off, 64);
  return v;
}
__device__ __forceinline__ float wave_max(float v) {
#pragma unroll
  for (int off = 32; off > 0; off >>= 1) v = fmaxf(v, __shfl_down(v, off, 64));
  return v;
}

// ---------------- weight ternary quant (i8) + per-row scale ----------------
__global__ __launch_bounds__(256) void wquant_kernel(
    const float* __restrict__ w, const float* __restrict__ row_scale,
    signed char* __restrict__ wq, float* __restrict__ scale, int K) {
  const int row = blockIdx.x;
  const int t = threadIdx.x;
  const float* wr = w + (size_t)row * K;
  float4 v0 = reinterpret_cast<const float4*>(wr)[2 * t];
  float4 v1 = reinterpret_cast<const float4*>(wr)[2 * t + 1];
  float f[8] = {v0.x, v0.y, v0.z, v0.w, v1.x, v1.y, v1.z, v1.w};
  float sa = 0.f, sq = 0.f;
#pragma unroll
  for (int i = 0; i < 8; ++i) { sa += fabsf(f[i]); sq += f[i] * f[i]; }
  sa = wave_sum(sa);
  sq = wave_sum(sq);
  __shared__ float smA[4], smQ[4];
  const int wid = t >> 6;
  if ((t & 63) == 0) { smA[wid] = sa; smQ[wid] = sq; }
  __syncthreads();
  const float sumabs = smA[0] + smA[1] + smA[2] + smA[3];
  const float sumsq  = smQ[0] + smQ[1] + smQ[2] + smQ[3];
  const float absmean = sumabs / (float)K;
  const float thr = 0.5f * absmean;
  union { signed char c[8]; uint2 u; } pk;
#pragma unroll
  for (int i = 0; i < 8; ++i)
    pk.c[i] = (fabsf(f[i]) > thr) ? (f[i] > 0.f ? (signed char)1 : (signed char)-1)
                                  : (signed char)0;
  reinterpret_cast<uint2*>(wq + (size_t)row * K)[t] = pk.u;
  if (t == 0)
    scale[row] = absmean * rsqrtf(sumsq / (float)K + EPSF) * row_scale[row];
}

// ---------------- input RMSNorm * g -> i8 (per-row symmetric) ----------------
__global__ __launch_bounds__(256) void xnorm_kernel(
    const float* __restrict__ x, const float* __restrict__ g,
    signed char* __restrict__ xq, float* __restrict__ sx, int K) {
  const int row = blockIdx.x;
  const int t = threadIdx.x;
  const float* xr = x + (size_t)row * K;
  float4 v0 = reinterpret_cast<const float4*>(xr)[2 * t];
  float4 v1 = reinterpret_cast<const float4*>(xr)[2 * t + 1];
  float f[8] = {v0.x, v0.y, v0.z, v0.w, v1.x, v1.y, v1.z, v1.w};
  float sq = 0.f;
#pragma unroll
  for (int i = 0; i < 8; ++i) sq += f[i] * f[i];
  sq = wave_sum(sq);
  __shared__ float smQ[4], smM[4];
  const int wid = t >> 6;
  if ((t & 63) == 0) smQ[wid] = sq;
  __syncthreads();
  const float sumsq = smQ[0] + smQ[1] + smQ[2] + smQ[3];
  const float rs = rsqrtf(sumsq / (float)K + EPSF);
  float4 g0 = reinterpret_cast<const float4*>(g)[2 * t];
  float4 g1 = reinterpret_cast<const float4*>(g)[2 * t + 1];
  float gg[8] = {g0.x, g0.y, g0.z, g0.w, g1.x, g1.y, g1.z, g1.w};
  float vv[8]; float am = 0.f;
#pragma unroll
  for (int i = 0; i < 8; ++i) {
    vv[i] = f[i] * rs * gg[i];
    am = fmaxf(am, fabsf(vv[i]));
  }
  am = wave_max(am);
  if ((t & 63) == 0) smM[wid] = am;
  __syncthreads();
  const float amax = fmaxf(fmaxf(smM[0], smM[1]), fmaxf(smM[2], smM[3]));
  const float inv = amax > 0.f ? 127.f / amax : 0.f;
  union { signed char c[8]; uint2 u; } pk;
#pragma unroll
  for (int i = 0; i < 8; ++i)
    pk.c[i] = (signed char)__float2int_rn(vv[i] * inv);
  reinterpret_cast<uint2*>(xq + (size_t)row * K)[t] = pk.u;
  if (t == 0) sx[row] = amax > 0.f ? amax / 127.f : 0.f;
}

// ---------------- i8 NT GEMM, 256x256 tile, 2-region pipeline ----------------
// C[m,n] = sx[m]*scale[n]*sum_k qA[m,k]*t[n,k] + bias[n]; i32 dot exact.
// 512 threads = 8 waves (2M x 4N); per-wave 128x64; BK=128 i8; 16x16x64 MFMA
// (R7's 32x32 regressed: 2 acc chains of depth 4 stall vs 8 chains of 2).
// ROUND-8: two barrier-regions per K-tile (was 4 phases):
//   [VM(counted); BAR; stage-issue; ds_reads; 32 MFMA]
// No manual lgkm, no sched_barrier inside the region: the compiler emits
// counted lgkmcnt between ds_read and first dependent MFMA, so read latency
// (and B-h1 reads) overlap the MFMA cluster instead of serializing per-phase.
// Stages AFTER the BAR: with reads after BAR, a pre-BAR stage could land in
// a slot another wave is still reading; post-BAR issue restores the
// one-barrier separation (readers of old data finish before their MFMAs,
// which precede the BAR the stager passed).
// vmcnt FIFO (loads; 1 half = 2 gld_lds). Steady entering R1(T0): 12
// {A0h0',B0h0',A0h1',B0h1',A1h0',B1h0'}:
//  R1(T0): VM(4) drains buf0 tile (8) | stage {A1h1,B1h1} -> 8
//  R2(T0): stage {A0h0',B0h0'} -> 12; reads A0h1 already drained
//  R1(T1): VM(4) drains {A1h0,B1h0,A1h1,B1h1} | stage {A0h1',B0h1'} -> 8
//  R2(T1): stage {A1h0',B1h0'} -> 12  => loop invariant holds.
// Prologue stages exactly the steady-state entering set (12 loads), so the
// loop head's VM(4)+BAR is the first sync. Peel: R1 VM(4), R1(T1) VM(0),
// stores inline after each quadrant's final MFMA.
// SQ_LDS_BANK_CONFLICT note: 6.29e6 = exactly 4 cyc/ds_read_b128 in BOTH the
// additive (R5) and XOR (R7) swizzles => b128-inherent counter artifact
// (1024B/wave through 32x4B banks = 8 bank-cycles min), not a fixable stall.

#define BAR() do { __builtin_amdgcn_sched_barrier(0); \
                   asm volatile("" ::: "memory"); \
                   __builtin_amdgcn_s_barrier(); \
                   asm volatile("" ::: "memory"); \
                   __builtin_amdgcn_sched_barrier(0); } while (0)
#define VM(n) asm volatile("s_waitcnt vmcnt(" #n ")" ::: "memory")

__global__ __launch_bounds__(512, 2) void gemm_kernel(
    const signed char* __restrict__ A,   // [M][K] i8 (xq)
    const signed char* __restrict__ B,   // [N][K] i8 ternary (wq)
    const float* __restrict__ scale, const float* __restrict__ bias,
    const float* __restrict__ sx,
    float* __restrict__ C, int M, int N, int K) {
  __shared__ signed char lds[2][2][2][16384];

  const int tid  = threadIdx.x;
  const int lane = tid & 63;
  const int wid  = tid >> 6;
  const int wm   = wid >> 2;   // 0..1
  const int wn   = wid & 3;    // 0..3
  const int fr   = lane & 15;
  const int kq   = lane >> 4;

  // chunked XCD swizzle (R2 mapping: all 8 bn co-resident per XCD)
  const int nwg = gridDim.x;
  const int cpx = nwg >> 3;
  const int swz = (blockIdx.x & 7) * cpx + (blockIdx.x >> 3);
  const int NBN = N >> 8;
  const int bn = swz % NBN;
  const int bm = swz / NBN;
  const int mBase = bm * 256, nBase = bn * 256;

  const size_t Kb = (size_t)K;  // bytes per row (i8)

  // staging: thread t -> lds row sr=t>>3, granule slot t&7; XOR-inverse
  // source granule (valid for +64-row second load: 64&7==0).
  const int sr = tid >> 3;                           // 0..63
  const int gsrc = (tid & 7) ^ (sr & 7);             // global granule
  const char* Abyte = (const char*)A + (size_t)(mBase + sr) * Kb + gsrc * 16;
  const char* Bbyte = (const char*)B +
      (size_t)(nBase + ((sr >> 5) * 64) + (sr & 31)) * Kb + gsrc * 16;

#define STAGE_A(bufi, h, t) do { \
    __builtin_amdgcn_global_load_lds( \
      (const __attribute__((address_space(1))) void*)(Abyte + (size_t)((h) * 64) * Kb + (size_t)(t) * 128), \
      (__attribute__((address_space(3))) void*)(&lds[bufi][0][h][tid * 16]), 16, 0, 0); \
    __builtin_amdgcn_global_load_lds( \
      (const __attribute__((address_space(1))) void*)(Abyte + (size_t)(128 + (h) * 64) * Kb + (size_t)(t) * 128), \
      (__attribute__((address_space(3))) void*)(&lds[bufi][0][h][8192 + tid * 16]), 16, 0, 0); \
  } while (0)

#define STAGE_B(bufi, h, t) do { \
    __builtin_amdgcn_global_load_lds( \
      (const __attribute__((address_space(1))) void*)(Bbyte + (size_t)((h) * 32) * Kb + (size_t)(t) * 128), \
      (__attribute__((address_space(3))) void*)(&lds[bufi][1][h][tid * 16]), 16, 0, 0); \
    __builtin_amdgcn_global_load_lds( \
      (const __attribute__((address_space(1))) void*)(Bbyte + (size_t)(128 + (h) * 32) * Kb + (size_t)(t) * 128), \
      (__attribute__((address_space(3))) void*)(&lds[bufi][1][h][8192 + tid * 16]), 16, 0, 0); \
  } while (0)

  // reader constants (XOR perm; fragment rows ≡ fr mod 8)
  const int slot0 = ((kq ^ (fr & 7)) << 4);   // byte offset, s=0 granule
  const int aRowB = (wm * 64 + fr) * 128;     // A lds row byte base
  const int bRowB = (wn * 32 + fr) * 128;     // B lds row byte base

  i32x4 aF[4][2], bF[4][2];
  i32x4 acc[8][4];
#pragma unroll
  for (int m = 0; m < 8; ++m)
#pragma unroll
    for (int n = 0; n < 4; ++n) acc[m][n] = (i32x4){0, 0, 0, 0};

#define LDA(bufi, mg) do { \
    _Pragma("unroll") for (int mm = 0; mm < 4; ++mm) \
    _Pragma("unroll") for (int s = 0; s < 2; ++s) \
      aF[mm][s] = *(const i32x4*)&lds[bufi][0][mg][ \
          aRowB + mm * 2048 + (slot0 ^ (s << 6))]; \
  } while (0)

#define LDB(bufi, np) do { \
    _Pragma("unroll") for (int nn = 0; nn < 2; ++nn) \
    _Pragma("unroll") for (int s = 0; s < 2; ++s) \
      bF[(np) * 2 + nn][s] = *(const i32x4*)&lds[bufi][1][np][ \
          bRowB + nn * 2048 + (slot0 ^ (s << 6))]; \
  } while (0)

#define MFMA_Q(mg, np) do { \
    __builtin_amdgcn_s_setprio(1); \
    _Pragma("unroll") for (int mm = 0; mm < 4; ++mm) \
    _Pragma("unroll") for (int nn = 0; nn < 2; ++nn) { \
      i32x4 c = acc[(mg) * 4 + mm][(np) * 2 + nn]; \
      c = __builtin_amdgcn_mfma_i32_16x16x64_i8(aF[mm][0], bF[(np) * 2 + nn][0], c, 0, 0, 0); \
      c = __builtin_amdgcn_mfma_i32_16x16x64_i8(aF[mm][1], bF[(np) * 2 + nn][1], c, 0, 0, 0); \
      acc[(mg) * 4 + mm][(np) * 2 + nn] = c; \
    } \
    __builtin_amdgcn_s_setprio(0); } while (0)

  const int crowBase = mBase + wm * 128 + kq * 4;
  const int ccolBase = nBase + wn * 64 + fr;

#define STORE_Q(mg, np) do { \
    float sxq_[4][4]; \
    _Pragma("unroll") for (int mm = 0; mm < 4; ++mm) \
    _Pragma("unroll") for (int r = 0; r < 4; ++r) \
      sxq_[mm][r] = sx[crowBase + ((mg) * 4 + mm) * 16 + r]; \
    _Pragma("unroll") for (int nn = 0; nn < 2; ++nn) { \
      const int gc = ccolBase + ((np) * 2 + nn) * 16; \
      const float sc = scale[gc]; \
      const float bi = bias[gc]; \
      _Pragma("unroll") for (int mm = 0; mm < 4; ++mm) { \
        const int r0 = crowBase + ((mg) * 4 + mm) * 16; \
        _Pragma("unroll") for (int r = 0; r < 4; ++r) \
          C[(size_t)(r0 + r) * (size_t)N + (size_t)gc] = \
              (float)acc[(mg) * 4 + mm][(np) * 2 + nn][r] * (sxq_[mm][r] * sc) + bi; \
      } } } while (0)

  // ---- prologue: exactly the steady-state entering set (12 loads) ----
  STAGE_A(0, 0, 0); STAGE_B(0, 0, 0);
  STAGE_A(0, 1, 0); STAGE_B(0, 1, 0);
  STAGE_A(1, 0, 1); STAGE_B(1, 0, 1);

  const int NT = K >> 7;  // 2048/128 = 16 K-tiles; 7 iters + peel
  for (int i = 0; i < (NT >> 1) - 1; ++i) {
    const int t1  = 2 * i + 1;
    const int tn0 = 2 * i + 2;
    const int tn1 = 2 * i + 3;
    // R1(T0)
    VM(4); BAR();
    STAGE_A(1, 1, t1); STAGE_B(1, 1, t1);
    LDA(0, 0); LDB(0, 0); LDB(0, 1);
    MFMA_Q(0, 0); MFMA_Q(0, 1);
    // R2(T0)
    BAR();
    STAGE_A(0, 0, tn0); STAGE_B(0, 0, tn0);
    LDA(0, 1);
    MFMA_Q(1, 0); MFMA_Q(1, 1);
    // R1(T1)
    VM(4); BAR();
    STAGE_A(0, 1, tn0); STAGE_B(0, 1, tn0);
    LDA(1, 0); LDB(1, 0); LDB(1, 1);
    MFMA_Q(0, 0); MFMA_Q(0, 1);
    // R2(T1)
    BAR();
    STAGE_A(1, 0, tn1); STAGE_B(1, 0, tn1);
    LDA(1, 1);
    MFMA_Q(1, 0); MFMA_Q(1, 1);
  }

  // ---- peeled last iteration (tiles NT-2 buf0, NT-1 buf1) ----
  {
    const int tl = NT - 1;
    // R1(T0)
    VM(4); BAR();
    STAGE_A(1, 1, tl); STAGE_B(1, 1, tl);
    LDA(0, 0); LDB(0, 0); LDB(0, 1);
    MFMA_Q(0, 0); MFMA_Q(0, 1);
    // R2(T0)
    BAR();
    LDA(0, 1);
    MFMA_Q(1, 0); MFMA_Q(1, 1);
    // R1(T1): drain everything; quadrants final from here -> store inline
    VM(0); BAR();
    LDA(1, 0); LDB(1, 0); LDB(1, 1);
    MFMA_Q(0, 0); STORE_Q(0, 0);
    MFMA_Q(0, 1); STORE_Q(0, 1);
    // R2(T1)
    BAR();
    LDA(1, 1);
    MFMA_Q(1, 0); STORE_Q(1, 0);
    MFMA_Q(1, 1); STORE_Q(1, 1);
  }
#undef STAGE_A
#undef STAGE_B
#undef LDA
#undef LDB
#undef MFMA_Q
#undef STORE_Q
}

extern "C" void kernel_launch(void* const* d_in, const int* in_sizes, int n_in,
                              void* d_out, int out_size, void* d_ws, size_t ws_size,
                              hipStream_t stream) {
  const float* x         = (const float*)d_in[0];  // [B,S,Din]
  const float* weight    = (const float*)d_in[1];  // [Dout,Din]
  const float* row_scale = (const float*)d_in[2];  // [Dout,1]
  const float* bias      = (const float*)d_in[3];  // [Dout]
  const float* g         = (const float*)d_in[4];  // [Din]
  float* out = (float*)d_out;

  const int Din  = in_sizes[4];         // 2048
  const int Dout = in_sizes[3];         // 2048
  const int Mrows = in_sizes[0] / Din;  // 16384

  // ws: wq i8 [Dout*Din] | xq i8 [M*Din] | scale f32 [Dout] | sx f32 [M]
  char* ws = (char*)d_ws;
  signed char* wq = (signed char*)ws;
  signed char* xq = (signed char*)(ws + (size_t)Dout * Din);
  float* scale = (float*)(ws + (size_t)Dout * Din + (size_t)Mrows * Din);
  float* sx = scale + Dout;

  wquant_kernel<<<Dout, 256, 0, stream>>>(weight, row_scale, wq, scale, Din);
  xnorm_kernel<<<Mrows, 256, 0, stream>>>(x, g, xq, sx, Din);
  const int grid = (Mrows / 256) * (Dout / 256);
  gemm_kernel<<<grid, 512, 0, stream>>>(xq, wq, scale, bias, sx, out,
                                        Mrows, Dout, Din);
}